// Round 7
// baseline (690.262 us; speedup 1.0000x reference)
//
#include <hip/hip_runtime.h>

#define EPSF 1e-6f

typedef __bf16 bf16;
typedef bf16 bf16x2 __attribute__((ext_vector_type(2)));
typedef bf16 bf16x4 __attribute__((ext_vector_type(4)));
typedef bf16 bf16x8 __attribute__((ext_vector_type(8)));
typedef float f32x4 __attribute__((ext_vector_type(4)));
typedef unsigned int u32;

// N=8, L=S=4096, E=256, H=8, D=32.
// R11: single NORMAL kernel launch + HAND-ROLLED grid barrier (no cooperative
// API, no cg). R10's failure isolated to grid-level machinery: cg::grid.sync
// under graph replay and/or missing reader-side post-barrier invalidate.
// Barrier here: syncthreads (drains vmcnt) -> tid0 {threadfence (L2 wb),
// agent atomicAdd, spin on agent atomic load} -> syncthreads -> threadfence
// by ALL threads (acquire invalidate — the piece R10 lacked). Counters in
// workspace, memsetAsync-zeroed each launch (graph-replay exact).
// Residency by construction: grid 1024, launch_bounds(256,4) (VGPR<=128),
// LDS 36864 -> 4 blocks/CU -> capacity == 1024.
// Phase bodies: P1 = R7 kvproj verbatim (single-buffer m97 pattern, proven);
// P3 = R6 l-tile-32 attn verbatim with R7's bf16-KVb frag path (proven);
// P2 = partial reduce; P0 = weight convert.

__device__ __forceinline__ void async_ld16(const void* g, void* l) {
    __builtin_amdgcn_global_load_lds(
        (const __attribute__((address_space(1))) u32*)g,
        (__attribute__((address_space(3))) u32*)l, 16, 0, 0);
}

__device__ __forceinline__ void gridbar(u32* cnt, u32 target) {
    __syncthreads();                 // all block stores vmcnt-drained (compiler)
    if (threadIdx.x == 0) {
        __threadfence();             // release: write back local L2
        __hip_atomic_fetch_add(cnt, 1u, __ATOMIC_ACQ_REL, __HIP_MEMORY_SCOPE_AGENT);
        while (__hip_atomic_load(cnt, __ATOMIC_ACQUIRE, __HIP_MEMORY_SCOPE_AGENT) < target)
            __builtin_amdgcn_s_sleep(2);
    }
    __syncthreads();
    __threadfence();                 // acquire: invalidate stale L1/L2 lines
}

__global__ __launch_bounds__(256, 4) void fused(
    const float* __restrict__ qin, const float* __restrict__ kin,
    const float* __restrict__ vin,
    const int* __restrict__ q_mask, const int* __restrict__ kv_mask,
    const float* __restrict__ Wqf, const float* __restrict__ bq,
    const float* __restrict__ Wkf, const float* __restrict__ bk,
    const float* __restrict__ Wvf, const float* __restrict__ bv,
    const float* __restrict__ Wmf,
    bf16* __restrict__ Wb, float* __restrict__ part,
    float* __restrict__ part_ks, bf16* __restrict__ KVb,
    float* __restrict__ Ksum, u32* __restrict__ bar,
    float* __restrict__ out)
{
    const int bid = blockIdx.x, t = threadIdx.x;
    const int lane = t & 63, w = t >> 6;
    const int ln15 = lane & 15, lg = lane >> 4;
    const int wbase = t & ~63;

    __shared__ __align__(16) char smem[36864];

    // ======== P0: weights f32 -> bf16 (first 512 blocks) ========
    if (bid < 512) {
        const int gi = bid * 512 + t * 2;
        const int m = gi >> 16;
        const float* S = (m == 0) ? Wqf : (m == 1) ? Wkf : (m == 2) ? Wvf : Wmf;
        const float2 vv = *(const float2*)(S + (gi & 65535));
        *(bf16x2*)(Wb + gi) = bf16x2{(bf16)vv.x, (bf16)vv.y};
    }
    gridbar(bar + 0, 1024u);

    // ======== P1: kvproj (R7 body verbatim; unit = (n, st, u)) ========
    // LDS: Kf [128][72] @0 (18432); Xs @18432 (8192); Ws @26624 (8192);
    //      Vm [128][72] @18432 aliases staging.
    {
        const int u  = bid & 1;
        const int j0 = u * 128;
        const int nst = bid >> 1;
        const int n  = nst >> 6;
        const int st = nst & 63;
        const int s0 = st * 64;
        const size_t R0 = (size_t)n * 4096 + s0;
        const int wn = w * 32;                 // wave's col base (one head)

        bf16*  Kf_ld = (bf16*)smem;
        float* Xs    = (float*)(smem + 18432);
        bf16*  Ws    = (bf16*)(smem + 18432 + 8192);
        bf16*  Vm_ld = (bf16*)(smem + 18432);

        float mv[4][4];
        #pragma unroll
        for (int mi = 0; mi < 4; ++mi)
            #pragma unroll
            for (int r = 0; r < 4; ++r)
                mv[mi][r] = kv_mask[R0 + mi * 16 + lg * 4 + r] ? 1.f : 0.f;

        #pragma unroll
        for (int z = 0; z < 2; ++z) {
            const float* X    = z ? vin : kin;
            const bf16*  W    = Wb + (size_t)(z + 1) * 65536;   // Wk, Wv
            const float* bias = z ? bv : bk;
            bf16* Yt          = z ? Vm_ld : Kf_ld;

            f32x4 acc[4][2] = {};

            for (int k0 = 0; k0 < 256; k0 += 32) {
                #pragma unroll
                for (int i = 0; i < 2; ++i) {  // X: 512 16B-slots
                    const int c = i * 256 + t, row = c >> 3, sc = c & 7;
                    async_ld16(X + (R0 + row) * 256 + k0 + ((sc ^ (row & 7)) * 4),
                               Xs + (size_t)(i * 256 + wbase) * 4);
                }
                #pragma unroll
                for (int i = 0; i < 2; ++i) {  // W: 512 slots, row-pair swizzle
                    const int c = i * 256 + t, g = c >> 3, c8 = c & 7;
                    const int c8s = c8 ^ (g & 7);
                    const int wrow = g * 2 + (c8s >> 2), gch = c8s & 3;
                    async_ld16(W + (size_t)(j0 + wrow) * 256 + k0 + gch * 8,
                               Ws + (size_t)(i * 256 + wbase) * 8);
                }
                __syncthreads();

                bf16x8 a[4], b[2];
                #pragma unroll
                for (int mi = 0; mi < 4; ++mi) {
                    const int r = mi * 16 + ln15, rb = r & 7;
                    f32x4 x0 = *(const f32x4*)&Xs[r * 32 + (((lg * 2)     ^ rb) * 4)];
                    f32x4 x1 = *(const f32x4*)&Xs[r * 32 + (((lg * 2 + 1) ^ rb) * 4)];
                    a[mi] = bf16x8{(bf16)x0[0], (bf16)x0[1], (bf16)x0[2], (bf16)x0[3],
                                   (bf16)x1[0], (bf16)x1[1], (bf16)x1[2], (bf16)x1[3]};
                }
                #pragma unroll
                for (int ni = 0; ni < 2; ++ni) {
                    const int wr = wn + ni * 16 + ln15, g = wr >> 1;
                    const int c8 = ((wr & 1) * 4 + lg) ^ (g & 7);
                    b[ni] = *(const bf16x8*)&Ws[g * 64 + c8 * 8];
                }
                #pragma unroll
                for (int mi = 0; mi < 4; ++mi)
                    #pragma unroll
                    for (int ni = 0; ni < 2; ++ni)
                        acc[mi][ni] = __builtin_amdgcn_mfma_f32_16x16x32_bf16(
                            a[mi], b[ni], acc[mi][ni], 0, 0, 0);
                __syncthreads();
            }

            float bb[2];
            #pragma unroll
            for (int ni = 0; ni < 2; ++ni) bb[ni] = bias[j0 + wn + ni * 16 + ln15];
            #pragma unroll
            for (int ni = 0; ni < 2; ++ni) {
                const int col = wn + ni * 16 + ln15;
                #pragma unroll
                for (int mi = 0; mi < 4; ++mi) {
                    const int rowb = mi * 16 + lg * 4;
                    bf16x4 pk;
                    #pragma unroll
                    for (int r = 0; r < 4; ++r) {
                        float x = acc[mi][ni][r] + bb[ni];
                        if (z == 0) x = (x > 0.f) ? (x + 1.f) : __expf(x);
                        pk[r] = (bf16)(x * mv[mi][r]);
                    }
                    *(bf16x4*)&Yt[col * 72 + rowb] = pk;
                }
            }
            __syncthreads();
        }

        // Ksum partials
        {
            const int c = t >> 1, sh = t & 1;
            const bf16* kp = Kf_ld + c * 72 + sh * 32;
            float s = 0.f;
            #pragma unroll
            for (int j = 0; j < 4; ++j) {
                bf16x8 vv = *(const bf16x8*)(kp + j * 8);
                #pragma unroll
                for (int jj = 0; jj < 8; ++jj) s += (float)vv[jj];
            }
            s += __shfl_xor(s, 1);
            if (sh == 0) part_ks[((size_t)(n * 64 + st)) * 256 + j0 + c] = s;
        }

        // partial KV: wave w -> head u*4+w, 32x32 over s=64
        {
            const int cb = wn;
            f32x4 c2[2][2] = {};
            #pragma unroll
            for (int step = 0; step < 2; ++step) {
                const int sb = step * 32 + lg * 8;
                bf16x8 a[2], b[2];
                #pragma unroll
                for (int mi = 0; mi < 2; ++mi)
                    a[mi] = *(const bf16x8*)&Kf_ld[(cb + mi * 16 + ln15) * 72 + sb];
                #pragma unroll
                for (int nj = 0; nj < 2; ++nj)
                    b[nj] = *(const bf16x8*)&Vm_ld[(cb + nj * 16 + ln15) * 72 + sb];
                #pragma unroll
                for (int mi = 0; mi < 2; ++mi)
                    #pragma unroll
                    for (int nj = 0; nj < 2; ++nj)
                        c2[mi][nj] = __builtin_amdgcn_mfma_f32_16x16x32_bf16(
                            a[mi], b[nj], c2[mi][nj], 0, 0, 0);
            }
            float* kvh = part + ((size_t)((n * 64 + st) * 8) + u * 4 + w) * 1024;
            #pragma unroll
            for (int mi = 0; mi < 2; ++mi)
                #pragma unroll
                for (int nj = 0; nj < 2; ++nj)
                    *(f32x4*)&kvh[(nj * 16 + ln15) * 32 + mi * 16 + lg * 4] = c2[mi][nj];
        }
    }
    gridbar(bar + 1, 1024u);

    // ======== P2: kv_reduce (1024 blocks: (nh, sixteenth)) ========
    {
        const int nh = bid >> 4, s16 = bid & 15;
        const int n = nh >> 3, h = nh & 7;
        if (t < 64) {
            const int off = s16 * 64 + t;
            float acc = 0.f;
            const float* p = part + ((size_t)n * 512 + h) * 1024 + off;
            #pragma unroll 8
            for (int c = 0; c < 64; ++c) acc += p[(size_t)c * 8192];
            KVb[(size_t)nh * 1024 + off] = (bf16)acc;
        } else if (s16 == 0 && t < 96) {
            const int c = t - 64;              // 0..31
            float s = 0.f;
            const float* pk = part_ks + (size_t)n * 16384 + h * 32 + c;
            for (int cc = 0; cc < 64; ++cc) s += pk[cc * 256];
            Ksum[n * 256 + h * 32 + c] = s;
        }
    }
    gridbar(bar + 2, 1024u);

    // ======== P3: attn (R6 l-tile-32 body; 1024 blocks = 8n x 128 lt) ========
    // LDS: Xs @0 (4096); Wst @4096 (16384); Qs [32][264] @0 aliases;
    //      KSs @20480 (1024); Dens @21504 (1152).
    {
        const int n = bid >> 7, l0 = (bid & 127) * 32;
        const size_t R0 = (size_t)n * 4096 + l0;
        const int wn = w * 64;
        const bf16* Wqb = Wb;
        const bf16* Wmb = Wb + 3 * 65536;

        float* Xs  = (float*)smem;
        bf16*  Wst = (bf16*)(smem + 4096);
        bf16 (*Qs)[264] = (bf16(*)[264])smem;
        float* KSs = (float*)(smem + 20480);
        float (*Dens)[9] = (float(*)[9])(smem + 21504);

        KSs[t] = Ksum[n * 256 + t];

        {   // Q-projection (single-buffer staged)
            f32x4 acc[2][4] = {};
            for (int k0 = 0; k0 < 256; k0 += 32) {
                {   // X: 256 slots (32 rows x 32 f32)
                    const int row = t >> 3, sc = t & 7;
                    async_ld16(qin + (R0 + row) * 256 + k0 + ((sc ^ (row & 7)) * 4),
                               Xs + (size_t)wbase * 4);
                }
                #pragma unroll
                for (int i = 0; i < 4; ++i) {  // W: 1024 slots (all 256 rows)
                    const int c = i * 256 + t, g = c >> 3, c8 = c & 7;
                    const int c8s = c8 ^ (g & 7);
                    const int wrow = g * 2 + (c8s >> 2), gch = c8s & 3;
                    async_ld16(Wqb + (size_t)wrow * 256 + k0 + gch * 8,
                               Wst + (size_t)(i * 256 + wbase) * 8);
                }
                __syncthreads();

                bf16x8 a[2], b[4];
                #pragma unroll
                for (int mi = 0; mi < 2; ++mi) {
                    const int r = mi * 16 + ln15, rb = r & 7;
                    f32x4 x0 = *(const f32x4*)&Xs[r * 32 + (((lg * 2)     ^ rb) * 4)];
                    f32x4 x1 = *(const f32x4*)&Xs[r * 32 + (((lg * 2 + 1) ^ rb) * 4)];
                    a[mi] = bf16x8{(bf16)x0[0], (bf16)x0[1], (bf16)x0[2], (bf16)x0[3],
                                   (bf16)x1[0], (bf16)x1[1], (bf16)x1[2], (bf16)x1[3]};
                }
                #pragma unroll
                for (int ni = 0; ni < 4; ++ni) {
                    const int wr = wn + ni * 16 + ln15, g = wr >> 1;
                    const int c8 = ((wr & 1) * 4 + lg) ^ (g & 7);
                    b[ni] = *(const bf16x8*)&Wst[g * 64 + c8 * 8];
                }
                #pragma unroll
                for (int mi = 0; mi < 2; ++mi)
                    #pragma unroll
                    for (int ni = 0; ni < 4; ++ni)
                        acc[mi][ni] = __builtin_amdgcn_mfma_f32_16x16x32_bf16(
                            a[mi], b[ni], acc[mi][ni], 0, 0, 0);
                __syncthreads();
            }
            float bb[4];
            #pragma unroll
            for (int ni = 0; ni < 4; ++ni) bb[ni] = bq[wn + ni * 16 + ln15];
            float mv[2][4];
            #pragma unroll
            for (int mi = 0; mi < 2; ++mi)
                #pragma unroll
                for (int r = 0; r < 4; ++r)
                    mv[mi][r] = q_mask[R0 + mi * 16 + lg * 4 + r] ? 1.f : 0.f;
            #pragma unroll
            for (int mi = 0; mi < 2; ++mi)
                #pragma unroll
                for (int r = 0; r < 4; ++r) {
                    const int row = mi * 16 + lg * 4 + r;
                    #pragma unroll
                    for (int ni = 0; ni < 4; ++ni) {
                        float x = acc[mi][ni][r] + bb[ni];
                        x = (x > 0.f) ? (x + 1.f) : __expf(x);
                        Qs[row][wn + ni * 16 + ln15] = (bf16)(x * mv[mi][r]);
                    }
                }
        }
        __syncthreads();

        {   // den[l][h]
            const int l = t & 31, h = t >> 5;
            float s = 0.f;
            #pragma unroll
            for (int d8 = 0; d8 < 4; ++d8) {
                bf16x8 qv = *(const bf16x8*)&Qs[l][h * 32 + d8 * 8];
                #pragma unroll
                for (int jj = 0; jj < 8; ++jj)
                    s += (float)qv[jj] * KSs[h * 32 + d8 * 8 + jj];
            }
            Dens[l][h] = s;
        }
        __syncthreads();

        #pragma unroll
        for (int hh = 0; hh < 2; ++hh) {       // num + normalize
            const int h = w * 2 + hh;
            const bf16* kvh = KVb + (size_t)(n * 8 + h) * 1024;
            bf16x8 a[2], b[2];
            #pragma unroll
            for (int mi = 0; mi < 2; ++mi)
                a[mi] = *(const bf16x8*)(kvh + (mi * 16 + ln15) * 32 + lg * 8);
            #pragma unroll
            for (int nj = 0; nj < 2; ++nj)
                b[nj] = *(const bf16x8*)&Qs[nj * 16 + ln15][h * 32 + lg * 8];
            f32x4 c[2][2];
            #pragma unroll
            for (int mi = 0; mi < 2; ++mi)
                #pragma unroll
                for (int nj = 0; nj < 2; ++nj) {
                    f32x4 zz = {};
                    c[mi][nj] = __builtin_amdgcn_mfma_f32_16x16x32_bf16(a[mi], b[nj], zz, 0, 0, 0);
                }
            #pragma unroll
            for (int nj = 0; nj < 2; ++nj) {
                const int l = nj * 16 + ln15;
                const float rcp = 1.f / (Dens[l][h] + EPSF);
                #pragma unroll
                for (int mi = 0; mi < 2; ++mi) {
                    bf16x4 pk;
                    #pragma unroll
                    for (int r = 0; r < 4; ++r) pk[r] = (bf16)(c[mi][nj][r] * rcp);
                    *(bf16x4*)&Qs[l][h * 32 + mi * 16 + lg * 4] = pk;
                }
            }
        }
        __syncthreads();

        {   // merge GEMM: out = Attn @ Wm^T
            f32x4 acc[2][4] = {};
            #pragma unroll 2
            for (int k0 = 0; k0 < 256; k0 += 32) {
                bf16x8 a[2], b[4];
                #pragma unroll
                for (int mi = 0; mi < 2; ++mi)
                    a[mi] = *(const bf16x8*)&Qs[mi * 16 + ln15][k0 + lg * 8];
                #pragma unroll
                for (int ni = 0; ni < 4; ++ni)
                    b[ni] = *(const bf16x8*)(Wmb + (size_t)(wn + ni * 16 + ln15) * 256 + k0 + lg * 8);
                #pragma unroll
                for (int mi = 0; mi < 2; ++mi)
                    #pragma unroll
                    for (int ni = 0; ni < 4; ++ni)
                        acc[mi][ni] = __builtin_amdgcn_mfma_f32_16x16x32_bf16(
                            a[mi], b[ni], acc[mi][ni], 0, 0, 0);
            }
            #pragma unroll
            for (int ni = 0; ni < 4; ++ni) {
                const int col = wn + ni * 16 + ln15;
                #pragma unroll
                for (int mi = 0; mi < 2; ++mi)
                    #pragma unroll
                    for (int r = 0; r < 4; ++r)
                        out[(R0 + mi * 16 + lg * 4 + r) * 256 + col] = acc[mi][ni][r];
            }
        }
    }
}

extern "C" void kernel_launch(void* const* d_in, const int* in_sizes, int n_in,
                              void* d_out, int out_size, void* d_ws, size_t ws_size,
                              hipStream_t stream) {
    const float* q      = (const float*)d_in[0];
    const float* k      = (const float*)d_in[1];
    const float* v      = (const float*)d_in[2];
    const int*   q_mask = (const int*)  d_in[3];
    const int*   kv_mask= (const int*)  d_in[4];
    const float* Wq     = (const float*)d_in[5];
    const float* bq     = (const float*)d_in[6];
    const float* Wk     = (const float*)d_in[7];
    const float* bk     = (const float*)d_in[8];
    const float* Wv     = (const float*)d_in[9];
    const float* bv     = (const float*)d_in[10];
    const float* Wm     = (const float*)d_in[11];

    char* ws = (char*)d_ws;
    bf16*  Wb      = (bf16*)ws;                                  // 524288 B
    float* part    = (float*)(ws + 524288);                      // 16777216 B
    float* part_ks = (float*)(ws + 524288 + 16777216);           // 524288 B
    bf16*  KVb     = (bf16*)(ws + 524288 + 16777216 + 524288);   // 131072 B
    float* Ksum    = (float*)(ws + 524288 + 16777216 + 524288 + 131072); // 8192 B
    u32*   bar     = (u32*)(ws + 17965056);                      // 16 B counters

    hipMemsetAsync(bar, 0, 16, stream);   // zero barrier counters (capture-safe)

    hipLaunchKernelGGL(fused, dim3(1024), dim3(256), 0, stream,
                       q, k, v, q_mask, kv_mask, Wq, bq, Wk, bk, Wv, bv, Wm,
                       Wb, part, part_ks, KVb, Ksum, bar, (float*)d_out);
}

// Round 8
// 195.455 us; speedup vs baseline: 3.5316x; 3.5316x over previous
//
#include <hip/hip_runtime.h>

#define EPSF 1e-6f

typedef __bf16 bf16;
typedef bf16 bf16x4 __attribute__((ext_vector_type(4)));
typedef bf16 bf16x8 __attribute__((ext_vector_type(8)));
typedef float f32x4 __attribute__((ext_vector_type(4)));
typedef unsigned int u32;

// N=8, L=S=4096, E=256, H=8, D=32.
// MFMA 16x16x32 bf16 frags: A[m=lane&15][k=(lane>>4)*8+j], B[k][n=lane&15],
// C/D: col=lane&15, row=(lane>>4)*4+reg.
//
// R12: revert to the proven 4-kernel split (R3/R7, 199.2us) — R11 showed
// inter-kernel gaps are small (replay period ~110us) and fusion has no
// upside — and merge kvproj's z-loop into ONE K-loop: per step stage
// Xk+Xv+Wk+Wv (32KB) and run 16 MFMAs. Halves the vmcnt-drain barrier
// count (16->8) with 2x compute per drain, at IDENTICAL LDS (36864B:
// staging fully dead post-loop, both Kf and Vm tiles alias it) -> still
// 4 blocks/CU, grid 1024 all-resident. attn/kv_reduce/wconv = R3 verbatim.

__device__ __forceinline__ void async_ld16(const void* g, void* l) {
    __builtin_amdgcn_global_load_lds(
        (const __attribute__((address_space(1))) u32*)g,
        (__attribute__((address_space(3))) u32*)l, 16, 0, 0);
}

__global__ __launch_bounds__(256) void wconv(
    const float* __restrict__ Wq, const float* __restrict__ Wk,
    const float* __restrict__ Wv, const float* __restrict__ Wm,
    bf16* __restrict__ Wb)
{
    const int b = blockIdx.x, t = threadIdx.x;
    const int m = b >> 6;
    const float* S = (m == 0) ? Wq : (m == 1) ? Wk : (m == 2) ? Wv : Wm;
    const int idx = (b & 63) * 1024 + t * 4;
    float4 v = *(const float4*)(S + idx);
    bf16x4 p = {(bf16)v.x, (bf16)v.y, (bf16)v.z, (bf16)v.w};
    *(bf16x4*)(Wb + (size_t)m * 65536 + idx) = p;
}

// ---------------------------------------------------------------------------
// kvproj (merged-z): per (coltile, n, s-tile64) block computes K-proj AND
// V-proj in ONE K-loop (16 MFMA/wave/step), then per-block partial KV
// (in-LDS MFMA) + Ksum partials, single coalesced stores. grid (2, 512).
// Wave layout: each wave = all 64 rows x 32 cols (= one head).
// LDS staging (in-loop): Xk f32 @0 (8192), Xv @8192, Wks @16384 (8192),
// Wvs @24576 (8192). Tiles (post-loop, alias staging): Kf [128][72] @0,
// Vm [128][72] @18432. Total 36864 -> 4 blocks/CU.
// part    layout: [n][st=64][h=8][v=32][d=32] f32 (16.78 MB)
// part_ks layout: [n][st=64][256] f32 (512 KB)
// ---------------------------------------------------------------------------
__global__ __launch_bounds__(256) void kvproj(
    const float* __restrict__ kin, const float* __restrict__ vin,
    const bf16* __restrict__ Wb,
    const float* __restrict__ bk, const float* __restrict__ bv,
    const int* __restrict__ kv_mask,
    float* __restrict__ part, float* __restrict__ part_ks)
{
    const int bx = blockIdx.x;                 // coltile (4 heads each)
    const int j0 = bx * 128;
    const int n  = blockIdx.y >> 6;
    const int st = blockIdx.y & 63;
    const int s0 = st * 64;
    const size_t R0 = (size_t)n * 4096 + s0;

    const int t = threadIdx.x, lane = t & 63, w = t >> 6;
    const int ln15 = lane & 15, lg = lane >> 4;
    const int wn = w * 32;                     // wave's col base (one head)
    const int wbase = t & ~63;

    __shared__ __align__(16) char smem[36864];
    float* Xk  = (float*)smem;                 // staging, in-loop only
    float* Xv  = (float*)(smem + 8192);
    bf16*  Wks = (bf16*)(smem + 16384);
    bf16*  Wvs = (bf16*)(smem + 24576);
    bf16*  Kf_ld = (bf16*)smem;                // [128 col][72 s], post-loop
    bf16*  Vm_ld = (bf16*)(smem + 18432);      // [128 col][72 s], post-loop

    const bf16* Wkg = Wb + (size_t)1 * 65536;
    const bf16* Wvg = Wb + (size_t)2 * 65536;

    // kv-mask for this tile's 64 rows
    float mv[4][4];
    #pragma unroll
    for (int mi = 0; mi < 4; ++mi)
        #pragma unroll
        for (int r = 0; r < 4; ++r)
            mv[mi][r] = kv_mask[R0 + mi * 16 + lg * 4 + r] ? 1.f : 0.f;

    f32x4 acck[4][2] = {}, accv[4][2] = {};

    for (int k0 = 0; k0 < 256; k0 += 32) {
        #pragma unroll
        for (int i = 0; i < 2; ++i) {          // Xk/Xv: 512 16B-slots each
            const int c = i * 256 + t, row = c >> 3, sc = c & 7;
            const size_t goff = (R0 + row) * 256 + k0 + ((sc ^ (row & 7)) * 4);
            async_ld16(kin + goff, Xk + (size_t)(i * 256 + wbase) * 4);
            async_ld16(vin + goff, Xv + (size_t)(i * 256 + wbase) * 4);
        }
        #pragma unroll
        for (int i = 0; i < 2; ++i) {          // Wk/Wv: 512 slots, row-pair swz
            const int c = i * 256 + t, g = c >> 3, c8 = c & 7;
            const int c8s = c8 ^ (g & 7);
            const int wrow = g * 2 + (c8s >> 2), gch = c8s & 3;
            const size_t woff = (size_t)(j0 + wrow) * 256 + k0 + gch * 8;
            async_ld16(Wkg + woff, Wks + (size_t)(i * 256 + wbase) * 8);
            async_ld16(Wvg + woff, Wvs + (size_t)(i * 256 + wbase) * 8);
        }
        __syncthreads();

        bf16x8 ak[4], av[4], bkf[2], bvf[2];
        #pragma unroll
        for (int mi = 0; mi < 4; ++mi) {
            const int r = mi * 16 + ln15, rb = r & 7;
            const int o0 = r * 32 + (((lg * 2)     ^ rb) * 4);
            const int o1 = r * 32 + (((lg * 2 + 1) ^ rb) * 4);
            f32x4 x0 = *(const f32x4*)&Xk[o0];
            f32x4 x1 = *(const f32x4*)&Xk[o1];
            ak[mi] = bf16x8{(bf16)x0[0], (bf16)x0[1], (bf16)x0[2], (bf16)x0[3],
                            (bf16)x1[0], (bf16)x1[1], (bf16)x1[2], (bf16)x1[3]};
            f32x4 y0 = *(const f32x4*)&Xv[o0];
            f32x4 y1 = *(const f32x4*)&Xv[o1];
            av[mi] = bf16x8{(bf16)y0[0], (bf16)y0[1], (bf16)y0[2], (bf16)y0[3],
                            (bf16)y1[0], (bf16)y1[1], (bf16)y1[2], (bf16)y1[3]};
        }
        #pragma unroll
        for (int ni = 0; ni < 2; ++ni) {
            const int wr = wn + ni * 16 + ln15, g = wr >> 1;
            const int c8 = ((wr & 1) * 4 + lg) ^ (g & 7);
            bkf[ni] = *(const bf16x8*)&Wks[g * 64 + c8 * 8];
            bvf[ni] = *(const bf16x8*)&Wvs[g * 64 + c8 * 8];
        }
        #pragma unroll
        for (int mi = 0; mi < 4; ++mi)
            #pragma unroll
            for (int ni = 0; ni < 2; ++ni) {
                acck[mi][ni] = __builtin_amdgcn_mfma_f32_16x16x32_bf16(
                    ak[mi], bkf[ni], acck[mi][ni], 0, 0, 0);
                accv[mi][ni] = __builtin_amdgcn_mfma_f32_16x16x32_bf16(
                    av[mi], bvf[ni], accv[mi][ni], 0, 0, 0);
            }
        __syncthreads();                       // staging reads done before reuse
    }

    // epilogue: K -> elu+1, mask -> Kf_ld; V -> mask -> Vm_ld (both alias
    // the now-dead staging; last loop barrier guarantees reads finished).
    // (No /s on Vm: reference's /s and *s cancel.)
    {
        float bbk[2], bbv[2];
        #pragma unroll
        for (int ni = 0; ni < 2; ++ni) {
            bbk[ni] = bk[j0 + wn + ni * 16 + ln15];
            bbv[ni] = bv[j0 + wn + ni * 16 + ln15];
        }
        #pragma unroll
        for (int ni = 0; ni < 2; ++ni) {
            const int col = wn + ni * 16 + ln15;
            #pragma unroll
            for (int mi = 0; mi < 4; ++mi) {
                const int rowb = mi * 16 + lg * 4;
                bf16x4 pk, pv;
                #pragma unroll
                for (int r = 0; r < 4; ++r) {
                    float xk2 = acck[mi][ni][r] + bbk[ni];
                    xk2 = (xk2 > 0.f) ? (xk2 + 1.f) : __expf(xk2);
                    pk[r] = (bf16)(xk2 * mv[mi][r]);
                    float xv2 = accv[mi][ni][r] + bbv[ni];
                    pv[r] = (bf16)(xv2 * mv[mi][r]);
                }
                *(bf16x4*)&Kf_ld[col * 72 + rowb] = pk;
                *(bf16x4*)&Vm_ld[col * 72 + rowb] = pv;
            }
        }
    }
    __syncthreads();                           // Kf/Vm visible to all waves

    // ---- Ksum partial: col-sums over this tile's 64 s-rows (stored once) ----
    {
        const int c = t >> 1, sh = t & 1;      // c in [0,128)
        const bf16* kp = Kf_ld + c * 72 + sh * 32;
        float s = 0.f;
        #pragma unroll
        for (int j = 0; j < 4; ++j) {
            bf16x8 vv = *(const bf16x8*)(kp + j * 8);
            #pragma unroll
            for (int jj = 0; jj < 8; ++jj) s += (float)vv[jj];
        }
        s += __shfl_xor(s, 1);
        if (sh == 0) part_ks[((size_t)(n * 64 + st)) * 256 + j0 + c] = s;
    }

    // ---- partial KV: wave w -> head bx*4+w, 32x32 over k-dim s=64 ----
    {
        const int cb = wn;                     // head-local col base in tile
        f32x4 c2[2][2] = {};
        #pragma unroll
        for (int step = 0; step < 2; ++step) {
            const int sb = step * 32 + lg * 8;
            bf16x8 a[2], b[2];
            #pragma unroll
            for (int mi = 0; mi < 2; ++mi)
                a[mi] = *(const bf16x8*)&Kf_ld[(cb + mi * 16 + ln15) * 72 + sb];
            #pragma unroll
            for (int nj = 0; nj < 2; ++nj)
                b[nj] = *(const bf16x8*)&Vm_ld[(cb + nj * 16 + ln15) * 72 + sb];
            #pragma unroll
            for (int mi = 0; mi < 2; ++mi)
                #pragma unroll
                for (int nj = 0; nj < 2; ++nj)
                    c2[mi][nj] = __builtin_amdgcn_mfma_f32_16x16x32_bf16(
                        a[mi], b[nj], c2[mi][nj], 0, 0, 0);
        }
        // D: col(v)=ln15, row(d)=lg*4+r -> store [v][d] (v-major), once.
        float* kvh = part + ((size_t)((n * 64 + st) * 8) + bx * 4 + w) * 1024;
        #pragma unroll
        for (int mi = 0; mi < 2; ++mi)
            #pragma unroll
            for (int nj = 0; nj < 2; ++nj)
                *(f32x4*)&kvh[(nj * 16 + ln15) * 32 + mi * 16 + lg * 4] = c2[mi][nj];
    }
}

// ---------------------------------------------------------------------------
// kv_reduce: sum 64 s-tile partials per (n,h) -> bf16 KVb + f32 Ksum.
// grid (256): block = (nh, quarter). ~17.3 MB read, coalesced.
// ---------------------------------------------------------------------------
__global__ __launch_bounds__(256) void kv_reduce(
    const float* __restrict__ part, const float* __restrict__ part_ks,
    bf16* __restrict__ KVb, float* __restrict__ Ksum)
{
    const int b = blockIdx.x;
    const int nh = b >> 2, q = b & 3;
    const int n = nh >> 3, h = nh & 7;
    const int t = threadIdx.x;
    const int off = q * 256 + t;               // element in [0,1024)
    float acc = 0.f;
    const float* p = part + ((size_t)n * 512 + h) * 1024 + off;
    #pragma unroll 8
    for (int c = 0; c < 64; ++c)
        acc += p[(size_t)c * 8192];
    KVb[(size_t)nh * 1024 + off] = (bf16)acc;
    if (q == 0 && t < 32) {
        float s = 0.f;
        const float* pk = part_ks + (size_t)n * 16384 + h * 32 + t;
        for (int c = 0; c < 64; ++c) s += pk[c * 256];
        Ksum[n * 256 + h * 32 + t] = s;
    }
}

// ---------------------------------------------------------------------------
// attn: fused Q-proj (staged core) + linear attention + merge GEMM.
// grid (64, 8), 64-row l-tile, 256 threads. bf16 KVb frags direct.
// (R3 body verbatim — proven at 199.2us.)
// ---------------------------------------------------------------------------
__global__ __launch_bounds__(256) void attn(
    const float* __restrict__ qin, const bf16* __restrict__ Wb,
    const float* __restrict__ bq, const int* __restrict__ q_mask,
    const bf16* __restrict__ KVb, const float* __restrict__ Ksum,
    float* __restrict__ out)
{
    const int n = blockIdx.y, l0 = blockIdx.x * 64;
    const size_t R0 = (size_t)n * 4096 + l0;
    const int t = threadIdx.x, lane = t & 63, w = t >> 6;
    const int ln15 = lane & 15, lg = lane >> 4;
    const int wn = w * 64;
    const int wbase = t & ~63;

    const bf16* Wq = Wb;
    const bf16* Wm = Wb + 3 * 65536;

    __shared__ __align__(16) char smem[33792];
    float* Xs  = (float*)smem;           //  8192 B: q tile 64x32 f32 swizzled
    bf16*  Wst = (bf16*)(smem + 8192);   // 16384 B: Wq tile 256x32 swizzled
    bf16 (*Qs)[264] = (bf16(*)[264])smem;
    __shared__ float KSs[256];
    __shared__ float Dens[64][9];

    KSs[t] = Ksum[n * 256 + t];

    {   // ---- Q-projection, staged ----
        f32x4 acc[4][4] = {};
        for (int k0 = 0; k0 < 256; k0 += 32) {
            #pragma unroll
            for (int i = 0; i < 2; ++i) {     // X: 512 slots
                const int c = i * 256 + t, row = c >> 3, sc = c & 7;
                async_ld16(qin + (R0 + row) * 256 + k0 + ((sc ^ (row & 7)) * 4),
                           Xs + (size_t)(i * 256 + wbase) * 4);
            }
            #pragma unroll
            for (int i = 0; i < 4; ++i) {     // W: 1024 slots (all 256 rows)
                const int c = i * 256 + t, g = c >> 3, c8 = c & 7;
                const int c8s = c8 ^ (g & 7);
                const int wrow = g * 2 + (c8s >> 2), gch = c8s & 3;
                async_ld16(Wq + (size_t)wrow * 256 + k0 + gch * 8,
                           Wst + (size_t)(i * 256 + wbase) * 8);
            }
            __syncthreads();

            bf16x8 a[4], b[4];
            #pragma unroll
            for (int mi = 0; mi < 4; ++mi) {
                const int r = mi * 16 + ln15, rb = r & 7;
                f32x4 x0 = *(const f32x4*)&Xs[r * 32 + (((lg * 2)     ^ rb) * 4)];
                f32x4 x1 = *(const f32x4*)&Xs[r * 32 + (((lg * 2 + 1) ^ rb) * 4)];
                a[mi] = bf16x8{(bf16)x0[0], (bf16)x0[1], (bf16)x0[2], (bf16)x0[3],
                               (bf16)x1[0], (bf16)x1[1], (bf16)x1[2], (bf16)x1[3]};
            }
            #pragma unroll
            for (int ni = 0; ni < 4; ++ni) {
                const int wr = wn + ni * 16 + ln15, g = wr >> 1;
                const int c8 = ((wr & 1) * 4 + lg) ^ (g & 7);
                b[ni] = *(const bf16x8*)&Wst[g * 64 + c8 * 8];
            }
            #pragma unroll
            for (int mi = 0; mi < 4; ++mi)
                #pragma unroll
                for (int ni = 0; ni < 4; ++ni)
                    acc[mi][ni] = __builtin_amdgcn_mfma_f32_16x16x32_bf16(
                        a[mi], b[ni], acc[mi][ni], 0, 0, 0);
            __syncthreads();
        }
        float bb[4];
        #pragma unroll
        for (int ni = 0; ni < 4; ++ni) bb[ni] = bq[wn + ni * 16 + ln15];
        float mv[4][4];
        #pragma unroll
        for (int mi = 0; mi < 4; ++mi)
            #pragma unroll
            for (int r = 0; r < 4; ++r)
                mv[mi][r] = q_mask[R0 + mi * 16 + lg * 4 + r] ? 1.f : 0.f;
        #pragma unroll
        for (int mi = 0; mi < 4; ++mi)
            #pragma unroll
            for (int r = 0; r < 4; ++r) {
                const int row = mi * 16 + lg * 4 + r;
                #pragma unroll
                for (int ni = 0; ni < 4; ++ni) {
                    float x = acc[mi][ni][r] + bb[ni];
                    x = (x > 0.f) ? (x + 1.f) : __expf(x);
                    Qs[row][wn + ni * 16 + ln15] = (bf16)(x * mv[mi][r]);
                }
            }
    }
    __syncthreads();

    #pragma unroll
    for (int i = 0; i < 2; ++i) {   // den[l][h]
        const int idx = t + i * 256;
        const int l = idx & 63, h = idx >> 6;
        float s = 0.f;
        #pragma unroll
        for (int d8 = 0; d8 < 4; ++d8) {
            bf16x8 qv = *(const bf16x8*)&Qs[l][h * 32 + d8 * 8];
            #pragma unroll
            for (int jj = 0; jj < 8; ++jj)
                s += (float)qv[jj] * KSs[h * 32 + d8 * 8 + jj];
        }
        Dens[l][h] = s;
    }
    __syncthreads();

    #pragma unroll
    for (int hh = 0; hh < 2; ++hh) {   // num + normalize (wave-disjoint cols)
        const int h = w * 2 + hh;
        const bf16* kvh = KVb + (size_t)(n * 8 + h) * 1024;
        bf16x8 a[2], b[4];
        #pragma unroll
        for (int mi = 0; mi < 2; ++mi)
            a[mi] = *(const bf16x8*)(kvh + (mi * 16 + ln15) * 32 + lg * 8);
        #pragma unroll
        for (int nj = 0; nj < 4; ++nj)
            b[nj] = *(const bf16x8*)&Qs[nj * 16 + ln15][h * 32 + lg * 8];
        f32x4 c[2][4];
        #pragma unroll
        for (int mi = 0; mi < 2; ++mi)
            #pragma unroll
            for (int nj = 0; nj < 4; ++nj) {
                f32x4 zz = {};
                c[mi][nj] = __builtin_amdgcn_mfma_f32_16x16x32_bf16(a[mi], b[nj], zz, 0, 0, 0);
            }
        #pragma unroll
        for (int nj = 0; nj < 4; ++nj) {
            const int l = nj * 16 + ln15;
            const float rcp = 1.f / (Dens[l][h] + EPSF);
            #pragma unroll
            for (int mi = 0; mi < 2; ++mi) {
                bf16x4 pk;
                #pragma unroll
                for (int r = 0; r < 4; ++r) pk[r] = (bf16)(c[mi][nj][r] * rcp);
                *(bf16x4*)&Qs[l][h * 32 + mi * 16 + lg * 4] = pk;
            }
        }
    }
    __syncthreads();

    {   // merge GEMM: out = Attn @ Wm^T (A from LDS, B from L2-hot Wm)
        f32x4 acc[4][4] = {};
        #pragma unroll 2
        for (int k0 = 0; k0 < 256; k0 += 32) {
            bf16x8 a[4], b[4];
            #pragma unroll
            for (int mi = 0; mi < 4; ++mi)
                a[mi] = *(const bf16x8*)&Qs[mi * 16 + ln15][k0 + lg * 8];
            #pragma unroll
            for (int ni = 0; ni < 4; ++ni)
                b[ni] = *(const bf16x8*)(Wm + (size_t)(wn + ni * 16 + ln15) * 256 + k0 + lg * 8);
            #pragma unroll
            for (int mi = 0; mi < 4; ++mi)
                #pragma unroll
                for (int ni = 0; ni < 4; ++ni)
                    acc[mi][ni] = __builtin_amdgcn_mfma_f32_16x16x32_bf16(
                        a[mi], b[ni], acc[mi][ni], 0, 0, 0);
        }
        #pragma unroll
        for (int ni = 0; ni < 4; ++ni) {
            const int col = wn + ni * 16 + ln15;
            #pragma unroll
            for (int mi = 0; mi < 4; ++mi)
                #pragma unroll
                for (int r = 0; r < 4; ++r)
                    out[(R0 + mi * 16 + lg * 4 + r) * 256 + col] = acc[mi][ni][r];
        }
    }
}

extern "C" void kernel_launch(void* const* d_in, const int* in_sizes, int n_in,
                              void* d_out, int out_size, void* d_ws, size_t ws_size,
                              hipStream_t stream) {
    const float* q      = (const float*)d_in[0];
    const float* k      = (const float*)d_in[1];
    const float* v      = (const float*)d_in[2];
    const int*   q_mask = (const int*)  d_in[3];
    const int*   kv_mask= (const int*)  d_in[4];
    const float* Wq     = (const float*)d_in[5];
    const float* bq     = (const float*)d_in[6];
    const float* Wk     = (const float*)d_in[7];
    const float* bk     = (const float*)d_in[8];
    const float* Wv     = (const float*)d_in[9];
    const float* bv     = (const float*)d_in[10];
    const float* Wm     = (const float*)d_in[11];

    char* ws = (char*)d_ws;
    bf16*  Wb      = (bf16*)ws;                                  // 524288 B
    float* part    = (float*)(ws + 524288);                      // 16777216 B
    float* part_ks = (float*)(ws + 524288 + 16777216);           // 524288 B
    bf16*  KVb     = (bf16*)(ws + 524288 + 16777216 + 524288);   // 131072 B
    float* Ksum    = (float*)(ws + 524288 + 16777216 + 524288 + 131072); // 8192 B

    const dim3 blk(256);
    wconv    <<<dim3(256),    blk, 0, stream>>>(Wq, Wk, Wv, Wm, Wb);
    kvproj   <<<dim3(2, 512), blk, 0, stream>>>(k, v, Wb, bk, bv, kv_mask, part, part_ks);
    kv_reduce<<<dim3(256),    blk, 0, stream>>>(part, part_ks, KVb, Ksum);
    attn     <<<dim3(64, 8),  blk, 0, stream>>>(q, Wb, bq, q_mask, KVb, Ksum, (float*)d_out);
}

// Round 9
// 194.828 us; speedup vs baseline: 3.5429x; 1.0032x over previous
//
#include <hip/hip_runtime.h>

#define EPSF 1e-6f

typedef __bf16 bf16;
typedef bf16 bf16x4 __attribute__((ext_vector_type(4)));
typedef bf16 bf16x8 __attribute__((ext_vector_type(8)));
typedef float f32x4 __attribute__((ext_vector_type(4)));
typedef unsigned int u32;

// N=8, L=S=4096, E=256, H=8, D=32.
// MFMA 16x16x32 bf16 frags: A[m=lane&15][k=(lane>>4)*8+j], B[k][n=lane&15],
// C/D: col=lane&15, row=(lane>>4)*4+reg.
//
// R13: COUNTED-vmcnt double-buffer pipeline (T4). R9's failure understood:
// its vmcnt(0) drain waited for the just-issued prefetch too, killing the
// overlap. Now: STAGE(next buf) -> s_waitcnt vmcnt(N) [N = loads just
// issued; the OLD buffer's loads are thereby complete, prefetch stays in
// flight] -> s_barrier -> compute(cur) -> lgkmcnt(0)+sched_barrier ->
// s_barrier [all reads done before next overwrite]. Every wave executes the
// same counted wait before each barrier => post-barrier the current buffer
// is complete chip-wide (the verified 8-phase template's discipline).
// Applied to kvproj (z-split dbuf, 51.2KB, 3 blocks/CU, vmcnt(4)) and
// attn's Q-proj (dbuf 2x24KB, vmcnt(6)). kv_reduce/wconv unchanged.

__device__ __forceinline__ void async_ld16(const void* g, void* l) {
    __builtin_amdgcn_global_load_lds(
        (const __attribute__((address_space(1))) u32*)g,
        (__attribute__((address_space(3))) u32*)l, 16, 0, 0);
}

#define VMCNT4() asm volatile("s_waitcnt vmcnt(4)" ::: "memory")
#define VMCNT6() asm volatile("s_waitcnt vmcnt(6)" ::: "memory")
#define VMCNT0() asm volatile("s_waitcnt vmcnt(0)" ::: "memory")
#define LGKM0()  asm volatile("s_waitcnt lgkmcnt(0)" ::: "memory")
#define SBAR()   __builtin_amdgcn_s_barrier()
#define SCHEDB() __builtin_amdgcn_sched_barrier(0)

__global__ __launch_bounds__(256) void wconv(
    const float* __restrict__ Wq, const float* __restrict__ Wk,
    const float* __restrict__ Wv, const float* __restrict__ Wm,
    bf16* __restrict__ Wb)
{
    const int b = blockIdx.x, t = threadIdx.x;
    const int m = b >> 6;
    const float* S = (m == 0) ? Wq : (m == 1) ? Wk : (m == 2) ? Wv : Wm;
    const int idx = (b & 63) * 1024 + t * 4;
    float4 v = *(const float4*)(S + idx);
    bf16x4 p = {(bf16)v.x, (bf16)v.y, (bf16)v.z, (bf16)v.w};
    *(bf16x4*)(Wb + (size_t)m * 65536 + idx) = p;
}

// ---------------------------------------------------------------------------
// kvproj (counted 2-phase pipeline): per (coltile, n, s-tile64) block computes
// K-proj AND V-proj tiles (z-loop, dbuf staging), then per-block partial KV
// (in-LDS MFMA) + Ksum partials, single coalesced stores. grid (2, 512).
// LDS: Kf [128][72] @0 (18432); staging dbuf @18432: buf b = Xs(8192)+Ws(8192)
//      at 18432+b*16384; Vm [128][72] @18432 aliases staging post-loop.
// Total 51200 B -> 3 blocks/CU.
// ---------------------------------------------------------------------------
__global__ __launch_bounds__(256) void kvproj(
    const float* __restrict__ kin, const float* __restrict__ vin,
    const bf16* __restrict__ Wb,
    const float* __restrict__ bk, const float* __restrict__ bv,
    const int* __restrict__ kv_mask,
    float* __restrict__ part, float* __restrict__ part_ks)
{
    const int bx = blockIdx.x;                 // coltile (4 heads each)
    const int j0 = bx * 128;
    const int n  = blockIdx.y >> 6;
    const int st = blockIdx.y & 63;
    const int s0 = st * 64;
    const size_t R0 = (size_t)n * 4096 + s0;

    const int t = threadIdx.x, lane = t & 63, w = t >> 6;
    const int ln15 = lane & 15, lg = lane >> 4;
    const int wn = w * 32;                     // wave's col base (one head)
    const int wbase = t & ~63;

    __shared__ __align__(16) char smem[51200];
    bf16* Kf_ld = (bf16*)smem;                 // [128 col][72 s]
    bf16* Vm_ld = (bf16*)(smem + 18432);       // [128][72], aliases staging

    // stage (buf b, source z, k-offset k0): 4 async 16B loads per thread
    auto STAGE = [&](int b, int zz, int k0) {
        const float* X = zz ? vin : kin;
        const bf16*  W = Wb + (size_t)(zz + 1) * 65536;
        float* Xs = (float*)(smem + 18432 + b * 16384);
        bf16*  Ws = (bf16*)(smem + 18432 + 8192 + b * 16384);
        #pragma unroll
        for (int i = 0; i < 2; ++i) {     // X: 512 16B-slots (64 rows x 32 f32)
            const int c = i * 256 + t, row = c >> 3, sc = c & 7;
            async_ld16(X + (R0 + row) * 256 + k0 + ((sc ^ (row & 7)) * 4),
                       Xs + (size_t)(i * 256 + wbase) * 4);
        }
        #pragma unroll
        for (int i = 0; i < 2; ++i) {     // W: 512 slots, swizzle over row-pairs
            const int c = i * 256 + t, g = c >> 3, c8 = c & 7;
            const int c8s = c8 ^ (g & 7);
            const int wrow = g * 2 + (c8s >> 2), gch = c8s & 3;
            async_ld16(W + (size_t)(j0 + wrow) * 256 + k0 + gch * 8,
                       Ws + (size_t)(i * 256 + wbase) * 8);
        }
    };

    // kv-mask for this tile's 64 rows (same for K and V phases)
    float mv[4][4];
    #pragma unroll
    for (int mi = 0; mi < 4; ++mi)
        #pragma unroll
        for (int r = 0; r < 4; ++r)
            mv[mi][r] = kv_mask[R0 + mi * 16 + lg * 4 + r] ? 1.f : 0.f;

    STAGE(0, 0, 0);                            // prologue: z=0, k0=0 -> buf0

    #pragma unroll
    for (int z = 0; z < 2; ++z) {
        const float* bias = z ? bv : bk;
        bf16* Yt          = z ? Vm_ld : Kf_ld;

        f32x4 acc[4][2] = {};

        #pragma unroll 2
        for (int t8 = 0; t8 < 8; ++t8) {
            const int cur = t8 & 1;
            // issue next-tile prefetch FIRST, then counted wait: the 4 loads
            // just issued stay in flight; the 4 older (buf[cur]) are complete.
            if (t8 < 7) {
                STAGE(cur ^ 1, z, (t8 + 1) * 32);
                VMCNT4();
            } else if (z == 0) {
                STAGE(cur ^ 1, 1, 0);          // prefetch z=1 first tile
                VMCNT4();
            } else {
                VMCNT0();                      // very last step: no prefetch
            }
            SCHEDB();
            SBAR();                            // all waves: buf[cur] complete

            const float* Xs = (const float*)(smem + 18432 + cur * 16384);
            const bf16*  Ws = (const bf16*)(smem + 18432 + 8192 + cur * 16384);

            bf16x8 a[4], b[2];
            #pragma unroll
            for (int mi = 0; mi < 4; ++mi) {
                const int r = mi * 16 + ln15, rb = r & 7;
                f32x4 x0 = *(const f32x4*)&Xs[r * 32 + (((lg * 2)     ^ rb) * 4)];
                f32x4 x1 = *(const f32x4*)&Xs[r * 32 + (((lg * 2 + 1) ^ rb) * 4)];
                a[mi] = bf16x8{(bf16)x0[0], (bf16)x0[1], (bf16)x0[2], (bf16)x0[3],
                               (bf16)x1[0], (bf16)x1[1], (bf16)x1[2], (bf16)x1[3]};
            }
            #pragma unroll
            for (int ni = 0; ni < 2; ++ni) {
                const int wr = wn + ni * 16 + ln15, g = wr >> 1;
                const int c8 = ((wr & 1) * 4 + lg) ^ (g & 7);
                b[ni] = *(const bf16x8*)&Ws[g * 64 + c8 * 8];
            }
            #pragma unroll
            for (int mi = 0; mi < 4; ++mi)
                #pragma unroll
                for (int ni = 0; ni < 2; ++ni)
                    acc[mi][ni] = __builtin_amdgcn_mfma_f32_16x16x32_bf16(
                        a[mi], b[ni], acc[mi][ni], 0, 0, 0);

            LGKM0();                           // my ds_reads complete
            SCHEDB();
            SBAR();                            // safe to overwrite buf[cur]
        }

        // epilogue: bias (+elu+1 for K), mask, transpose to [col][s] in LDS.
        // z=0: Kf_ld disjoint from staging. z=1: Vm_ld aliases staging; the
        // loop's trailing LGKM0+SBAR guarantees all waves' reads are done,
        // and vmcnt==0 (no prefetch on last step). (No /s on Vm: /s and *s
        // cancel.)
        float bb[2];
        #pragma unroll
        for (int ni = 0; ni < 2; ++ni) bb[ni] = bias[j0 + wn + ni * 16 + ln15];
        #pragma unroll
        for (int ni = 0; ni < 2; ++ni) {
            const int col = wn + ni * 16 + ln15;
            #pragma unroll
            for (int mi = 0; mi < 4; ++mi) {
                const int rowb = mi * 16 + lg * 4;
                bf16x4 pk;
                #pragma unroll
                for (int r = 0; r < 4; ++r) {
                    float x = acc[mi][ni][r] + bb[ni];
                    if (z == 0) x = (x > 0.f) ? (x + 1.f) : __expf(x);
                    pk[r] = (bf16)(x * mv[mi][r]);
                }
                *(bf16x4*)&Yt[col * 72 + rowb] = pk;
            }
        }
    }
    __syncthreads();                           // Kf/Vm visible to all waves

    // ---- Ksum partial: col-sums over this tile's 64 s-rows (stored once) ----
    {
        const int c = t >> 1, sh = t & 1;      // c in [0,128)
        const bf16* kp = Kf_ld + c * 72 + sh * 32;
        float s = 0.f;
        #pragma unroll
        for (int j = 0; j < 4; ++j) {
            bf16x8 vv = *(const bf16x8*)(kp + j * 8);
            #pragma unroll
            for (int jj = 0; jj < 8; ++jj) s += (float)vv[jj];
        }
        s += __shfl_xor(s, 1);
        if (sh == 0) part_ks[((size_t)(n * 64 + st)) * 256 + j0 + c] = s;
    }

    // ---- partial KV: wave w -> head bx*4+w, 32x32 over k-dim s=64 ----
    {
        const int cb = wn;                     // head-local col base in tile
        f32x4 c2[2][2] = {};
        #pragma unroll
        for (int step = 0; step < 2; ++step) {
            const int sb = step * 32 + lg * 8;
            bf16x8 a[2], b[2];
            #pragma unroll
            for (int mi = 0; mi < 2; ++mi)
                a[mi] = *(const bf16x8*)&Kf_ld[(cb + mi * 16 + ln15) * 72 + sb];
            #pragma unroll
            for (int nj = 0; nj < 2; ++nj)
                b[nj] = *(const bf16x8*)&Vm_ld[(cb + nj * 16 + ln15) * 72 + sb];
            #pragma unroll
            for (int mi = 0; mi < 2; ++mi)
                #pragma unroll
                for (int nj = 0; nj < 2; ++nj)
                    c2[mi][nj] = __builtin_amdgcn_mfma_f32_16x16x32_bf16(
                        a[mi], b[nj], c2[mi][nj], 0, 0, 0);
        }
        // D: col(v)=ln15, row(d)=lg*4+r -> store [v][d] (v-major), once.
        float* kvh = part + ((size_t)((n * 64 + st) * 8) + bx * 4 + w) * 1024;
        #pragma unroll
        for (int mi = 0; mi < 2; ++mi)
            #pragma unroll
            for (int nj = 0; nj < 2; ++nj)
                *(f32x4*)&kvh[(nj * 16 + ln15) * 32 + mi * 16 + lg * 4] = c2[mi][nj];
    }
}

// ---------------------------------------------------------------------------
// kv_reduce: sum 64 s-tile partials per (n,h) -> bf16 KVb + f32 Ksum.
// grid (256): block = (nh, quarter). ~17.3 MB read, coalesced.
// ---------------------------------------------------------------------------
__global__ __launch_bounds__(256) void kv_reduce(
    const float* __restrict__ part, const float* __restrict__ part_ks,
    bf16* __restrict__ KVb, float* __restrict__ Ksum)
{
    const int b = blockIdx.x;
    const int nh = b >> 2, q = b & 3;
    const int n = nh >> 3, h = nh & 7;
    const int t = threadIdx.x;
    const int off = q * 256 + t;               // element in [0,1024)
    float acc = 0.f;
    const float* p = part + ((size_t)n * 512 + h) * 1024 + off;
    #pragma unroll 8
    for (int c = 0; c < 64; ++c)
        acc += p[(size_t)c * 8192];
    KVb[(size_t)nh * 1024 + off] = (bf16)acc;
    if (q == 0 && t < 32) {
        float s = 0.f;
        const float* pk = part_ks + (size_t)n * 16384 + h * 32 + t;
        for (int c = 0; c < 64; ++c) s += pk[c * 256];
        Ksum[n * 256 + h * 32 + t] = s;
    }
}

// ---------------------------------------------------------------------------
// attn: fused Q-proj (counted 2-phase pipeline) + linear attention + merge
// GEMM. grid (64, 8), 64-row l-tile, 256 threads. bf16 KVb frags direct.
// LDS: staging dbuf @0: buf b = Xs(8192)+Wst(16384) at b*24576 (49152 B);
//      Qs [64][264] @0 aliases staging post-loop.
// ---------------------------------------------------------------------------
__global__ __launch_bounds__(256) void attn(
    const float* __restrict__ qin, const bf16* __restrict__ Wb,
    const float* __restrict__ bq, const int* __restrict__ q_mask,
    const bf16* __restrict__ KVb, const float* __restrict__ Ksum,
    float* __restrict__ out)
{
    const int n = blockIdx.y, l0 = blockIdx.x * 64;
    const size_t R0 = (size_t)n * 4096 + l0;
    const int t = threadIdx.x, lane = t & 63, w = t >> 6;
    const int ln15 = lane & 15, lg = lane >> 4;
    const int wn = w * 64;
    const int wbase = t & ~63;

    const bf16* Wq = Wb;
    const bf16* Wm = Wb + 3 * 65536;

    __shared__ __align__(16) char smem[49152];
    bf16 (*Qs)[264] = (bf16(*)[264])smem;      // 33792 B, aliases staging
    __shared__ float KSs[256];
    __shared__ float Dens[64][9];

    auto STAGE = [&](int b, int k0) {          // 6 async 16B loads per thread
        float* Xs  = (float*)(smem + b * 24576);
        bf16*  Wst = (bf16*)(smem + b * 24576 + 8192);
        #pragma unroll
        for (int i = 0; i < 2; ++i) {     // X: 512 slots
            const int c = i * 256 + t, row = c >> 3, sc = c & 7;
            async_ld16(qin + (R0 + row) * 256 + k0 + ((sc ^ (row & 7)) * 4),
                       Xs + (size_t)(i * 256 + wbase) * 4);
        }
        #pragma unroll
        for (int i = 0; i < 4; ++i) {     // W: 1024 slots (all 256 rows)
            const int c = i * 256 + t, g = c >> 3, c8 = c & 7;
            const int c8s = c8 ^ (g & 7);
            const int wrow = g * 2 + (c8s >> 2), gch = c8s & 3;
            async_ld16(Wq + (size_t)wrow * 256 + k0 + gch * 8,
                       Wst + (size_t)(i * 256 + wbase) * 8);
        }
    };

    STAGE(0, 0);
    KSs[t] = Ksum[n * 256 + t];

    {   // ---- Q-projection, counted 2-phase pipeline ----
        f32x4 acc[4][4] = {};
        #pragma unroll 2
        for (int t8 = 0; t8 < 8; ++t8) {
            const int cur = t8 & 1;
            if (t8 < 7) {
                STAGE(cur ^ 1, (t8 + 1) * 32);
                VMCNT6();                      // 6 new in flight; buf[cur] done
            } else {
                VMCNT0();
            }
            SCHEDB();
            SBAR();

            const float* Xs  = (const float*)(smem + cur * 24576);
            const bf16*  Wst = (const bf16*)(smem + cur * 24576 + 8192);

            bf16x8 a[4], b[4];
            #pragma unroll
            for (int mi = 0; mi < 4; ++mi) {
                const int r = mi * 16 + ln15, rb = r & 7;
                f32x4 x0 = *(const f32x4*)&Xs[r * 32 + (((lg * 2)     ^ rb) * 4)];
                f32x4 x1 = *(const f32x4*)&Xs[r * 32 + (((lg * 2 + 1) ^ rb) * 4)];
                a[mi] = bf16x8{(bf16)x0[0], (bf16)x0[1], (bf16)x0[2], (bf16)x0[3],
                               (bf16)x1[0], (bf16)x1[1], (bf16)x1[2], (bf16)x1[3]};
            }
            #pragma unroll
            for (int ni = 0; ni < 4; ++ni) {
                const int wr = wn + ni * 16 + ln15, g = wr >> 1;
                const int c8 = ((wr & 1) * 4 + lg) ^ (g & 7);
                b[ni] = *(const bf16x8*)&Wst[g * 64 + c8 * 8];
            }
            #pragma unroll
            for (int mi = 0; mi < 4; ++mi)
                #pragma unroll
                for (int ni = 0; ni < 4; ++ni)
                    acc[mi][ni] = __builtin_amdgcn_mfma_f32_16x16x32_bf16(
                        a[mi], b[ni], acc[mi][ni], 0, 0, 0);

            LGKM0();
            SCHEDB();
            SBAR();
        }

        // epilogue writes Qs (aliases staging): loop's trailing LGKM0+SBAR
        // means all reads done, vmcnt==0 (no prefetch on last step).
        float bb[4];
        #pragma unroll
        for (int ni = 0; ni < 4; ++ni) bb[ni] = bq[wn + ni * 16 + ln15];
        float mv[4][4];
        #pragma unroll
        for (int mi = 0; mi < 4; ++mi)
            #pragma unroll
            for (int r = 0; r < 4; ++r)
                mv[mi][r] = q_mask[R0 + mi * 16 + lg * 4 + r] ? 1.f : 0.f;
        #pragma unroll
        for (int mi = 0; mi < 4; ++mi)
            #pragma unroll
            for (int r = 0; r < 4; ++r) {
                const int row = mi * 16 + lg * 4 + r;
                #pragma unroll
                for (int ni = 0; ni < 4; ++ni) {
                    float x = acc[mi][ni][r] + bb[ni];
                    x = (x > 0.f) ? (x + 1.f) : __expf(x);
                    Qs[row][wn + ni * 16 + ln15] = (bf16)(x * mv[mi][r]);
                }
            }
    }
    __syncthreads();

    #pragma unroll
    for (int i = 0; i < 2; ++i) {   // den[l][h]
        const int idx = t + i * 256;
        const int l = idx & 63, h = idx >> 6;
        float s = 0.f;
        #pragma unroll
        for (int d8 = 0; d8 < 4; ++d8) {
            bf16x8 qv = *(const bf16x8*)&Qs[l][h * 32 + d8 * 8];
            #pragma unroll
            for (int jj = 0; jj < 8; ++jj)
                s += (float)qv[jj] * KSs[h * 32 + d8 * 8 + jj];
        }
        Dens[l][h] = s;
    }
    __syncthreads();

    #pragma unroll
    for (int hh = 0; hh < 2; ++hh) {   // num + normalize (wave-disjoint cols)
        const int h = w * 2 + hh;
        const bf16* kvh = KVb + (size_t)(n * 8 + h) * 1024;
        bf16x8 a[2], b[4];
        #pragma unroll
        for (int mi = 0; mi < 2; ++mi)
            a[mi] = *(const bf16x8*)(kvh + (mi * 16 + ln15) * 32 + lg * 8);
        #pragma unroll
        for (int nj = 0; nj < 4; ++nj)
            b[nj] = *(const bf16x8*)&Qs[nj * 16 + ln15][h * 32 + lg * 8];
        f32x4 c[2][4];
        #pragma unroll
        for (int mi = 0; mi < 2; ++mi)
            #pragma unroll
            for (int nj = 0; nj < 4; ++nj) {
                f32x4 zz = {};
                c[mi][nj] = __builtin_amdgcn_mfma_f32_16x16x32_bf16(a[mi], b[nj], zz, 0, 0, 0);
            }
        #pragma unroll
        for (int nj = 0; nj < 4; ++nj) {
            const int l = nj * 16 + ln15;
            const float rcp = 1.f / (Dens[l][h] + EPSF);
            #pragma unroll
            for (int mi = 0; mi < 2; ++mi) {
                bf16x4 pk;
                #pragma unroll
                for (int r = 0; r < 4; ++r) pk[r] = (bf16)(c[mi][nj][r] * rcp);
                *(bf16x4*)&Qs[l][h * 32 + mi * 16 + lg * 4] = pk;
            }
        }
    }
    __syncthreads();

    {   // merge GEMM: out = Attn @ Wm^T (A from LDS, B from L2-hot Wm)
        f32x4 acc[4][4] = {};
        #pragma unroll 2
        for (int k0 = 0; k0 < 256; k0 += 32) {
            bf16x8 a[4], b[4];
            #pragma unroll
            for (int mi = 0; mi < 4; ++mi)
                a[mi] = *(const bf16x8*)&Qs[mi * 16 + ln15][k0 + lg * 8];
            #pragma unroll
            for (int ni = 0; ni < 4; ++ni)
                b[ni] = *(const bf16x8*)(Wm + (size_t)(wn + ni * 16 + ln15) * 256 + k0 + lg * 8);
            #pragma unroll
            for (int mi = 0; mi < 4; ++mi)
                #pragma unroll
                for (int ni = 0; ni < 4; ++ni)
                    acc[mi][ni] = __builtin_amdgcn_mfma_f32_16x16x32_bf16(
                        a[mi], b[ni], acc[mi][ni], 0, 0, 0);
        }
        #pragma unroll
        for (int ni = 0; ni < 4; ++ni) {
            const int col = wn + ni * 16 + ln15;
            #pragma unroll
            for (int mi = 0; mi < 4; ++mi)
                #pragma unroll
                for (int r = 0; r < 4; ++r)
                    out[(R0 + mi * 16 + lg * 4 + r) * 256 + col] = acc[mi][ni][r];
        }
    }
}

extern "C" void kernel_launch(void* const* d_in, const int* in_sizes, int n_in,
                              void* d_out, int out_size, void* d_ws, size_t ws_size,
                              hipStream_t stream) {
    const float* q      = (const float*)d_in[0];
    const float* k      = (const float*)d_in[1];
    const float* v      = (const float*)d_in[2];
    const int*   q_mask = (const int*)  d_in[3];
    const int*   kv_mask= (const int*)  d_in[4];
    const float* Wq     = (const float*)d_in[5];
    const float* bq     = (const float*)d_in[6];
    const float* Wk     = (const float*)d_in[7];
    const float* bk     = (const float*)d_in[8];
    const float* Wv     = (const float*)d_in[9];
    const float* bv     = (const float*)d_in[10];
    const float* Wm     = (const float*)d_in[11];

    char* ws = (char*)d_ws;
    bf16*  Wb      = (bf16*)ws;                                  // 524288 B
    float* part    = (float*)(ws + 524288);                      // 16777216 B
    float* part_ks = (float*)(ws + 524288 + 16777216);           // 524288 B
    bf16*  KVb     = (bf16*)(ws + 524288 + 16777216 + 524288);   // 131072 B
    float* Ksum    = (float*)(ws + 524288 + 16777216 + 524288 + 131072); // 8192 B

    const dim3 blk(256);
    wconv    <<<dim3(256),    blk, 0, stream>>>(Wq, Wk, Wv, Wm, Wb);
    kvproj   <<<dim3(2, 512), blk, 0, stream>>>(k, v, Wb, bk, bv, kv_mask, part, part_ks);
    kv_reduce<<<dim3(256),    blk, 0, stream>>>(part, part_ks, KVb, Ksum);
    attn     <<<dim3(64, 8),  blk, 0, stream>>>(q, Wb, bq, q_mask, KVb, Ksum, (float*)d_out);
}